// Round 2
// baseline (857.418 us; speedup 1.0000x reference)
//
#include <hip/hip_runtime.h>
#include <hip/hip_bf16.h>

// HDSR social-graph propagation, MI355X.
// CSR-by-dst built once per launch (edge_index fixed across layers), then 3x
// node-centric weighted gather (wave per node, 4 edges x 16 lanes x float4).
// Softmax max-shift elided (attr in [0,1), exp safe; ratio identical).
// gcn_norm dis[] reduces to a {0,1} flag since softmax weights sum to 1.
// CSR payload packed as int2 {src | mask3<<18, exp_bits} - one 8B load/edge.

constexpr int N  = 150001;
constexpr int E  = 3000000;
constexpr int NB = (N + 255) / 256;   // 587 blocks for node-parallel kernels
constexpr int PB = (N + 3) / 4;       // 4 waves/block, wave per node

// ---------------- dtype detection (int64-vs-int32 indices, u8-vs-i32 mask) ----
__global__ void detect_kernel(const unsigned int* __restrict__ ei_w,
                              const unsigned int* __restrict__ mask_w,
                              int* __restrict__ flags) {
    __shared__ int hi_nonzero, not01;
    if (threadIdx.x == 0) { hi_nonzero = 0; not01 = 0; }
    __syncthreads();
    for (int i = threadIdx.x; i < 4096; i += blockDim.x) {
        if (ei_w[2 * i + 1] != 0u) hi_nonzero = 1;  // int32 layout: odd words are random ids
        if (mask_w[i] > 1u)        not01 = 1;       // byte-packed bools: e.g. 0x01000101
    }
    __syncthreads();
    if (threadIdx.x == 0) {
        flags[0] = (hi_nonzero == 0) ? 1 : 0;  // 1 => indices are int64
        flags[1] = not01;                       // 1 => mask is 1-byte bools
    }
}

__device__ __forceinline__ int load_node(const void* ei, int idx, int f64) {
    return f64 ? (int)((const long long*)ei)[idx] : ((const int*)ei)[idx];
}

// ---------------- CSR build -------------------------------------------------
__global__ void hist_kernel(const void* __restrict__ ei, const int* __restrict__ flags,
                            int* __restrict__ cnt) {
    const int f64 = flags[0];
    for (int e = blockIdx.x * blockDim.x + threadIdx.x; e < E; e += gridDim.x * blockDim.x) {
        const int d = load_node(ei, E + e, f64);
        atomicAdd(&cnt[d], 1);
    }
}

__global__ void scan_k1(const int* __restrict__ cnt, int* __restrict__ bsums) {
    __shared__ int sd[256];
    const int t = threadIdx.x;
    const int i = blockIdx.x * 256 + t;
    sd[t] = (i < N) ? cnt[i] : 0;
    __syncthreads();
    for (int off = 128; off > 0; off >>= 1) {
        if (t < off) sd[t] += sd[t + off];
        __syncthreads();
    }
    if (t == 0) bsums[blockIdx.x] = sd[0];
}

__global__ void scan_k2(int* __restrict__ bsums) {
    __shared__ int sd[1024];
    const int t = threadIdx.x;
    const int v = (t < NB) ? bsums[t] : 0;
    sd[t] = v;
    __syncthreads();
    for (int off = 1; off < 1024; off <<= 1) {
        int tmp = 0;
        if (t >= off) tmp = sd[t - off];
        __syncthreads();
        if (t >= off) sd[t] += tmp;
        __syncthreads();
    }
    if (t < NB) bsums[t] = sd[t] - v;  // exclusive scan of block sums
}

__global__ void scan_k3(const int* __restrict__ cnt, const int* __restrict__ bsums,
                        int* __restrict__ offsets, int* __restrict__ cursor) {
    __shared__ int sd[256];
    const int t = threadIdx.x;
    const int i = blockIdx.x * 256 + t;
    const int v = (i < N) ? cnt[i] : 0;
    sd[t] = v;
    __syncthreads();
    for (int off = 1; off < 256; off <<= 1) {
        int tmp = 0;
        if (t >= off) tmp = sd[t - off];
        __syncthreads();
        if (t >= off) sd[t] += tmp;
        __syncthreads();
    }
    const int excl = bsums[blockIdx.x] + sd[t] - v;
    if (i < N) { offsets[i] = excl; cursor[i] = excl; }
    if (i == 0) offsets[N] = E;
}

// csr[p] = { src | mask3<<18 , float_bits(exp(attr)) }
__global__ void scatter_kernel(const void* __restrict__ ei, const void* __restrict__ maskp,
                               const float* __restrict__ attr, const int* __restrict__ flags,
                               int* __restrict__ cursor, int2* __restrict__ csr) {
    const int f64 = flags[0], fu8 = flags[1];
    const unsigned char* m8 = (const unsigned char*)maskp;
    const int* m32 = (const int*)maskp;
    for (int e = blockIdx.x * blockDim.x + threadIdx.x; e < E; e += gridDim.x * blockDim.x) {
        const int s_ = load_node(ei, e, f64);
        const int d  = load_node(ei, E + e, f64);
        unsigned int mb;
        if (fu8) mb = (m8[e]  ? 1u : 0u) | (m8[E + e]  ? 2u : 0u) | (m8[2 * E + e]  ? 4u : 0u);
        else     mb = (m32[e] ? 1u : 0u) | (m32[E + e] ? 2u : 0u) | (m32[2 * E + e] ? 4u : 0u);
        const int pos = atomicAdd(&cursor[d], 1);
        csr[pos] = make_int2(s_ | (int)(mb << 18), __float_as_int(__expf(attr[e]) ));
    }
}

// ---------------- per-layer softmax denominators (all 3 layers, one pass) ----
__global__ __launch_bounds__(256) void sums_kernel(const int* __restrict__ offsets,
                                                   const int2* __restrict__ csr,
                                                   float* __restrict__ sarr) {
    const int n = blockIdx.x * blockDim.x + threadIdx.x;
    if (n >= N) return;
    const int beg = offsets[n], end = offsets[n + 1];
    float s0 = 0.f, s1 = 0.f, s2 = 0.f;
    for (int p = beg; p < end; ++p) {
        const int2 v = csr[p];
        const float ex = __int_as_float(v.y);
        if (v.x & (1 << 18)) s0 += ex;
        if (v.x & (1 << 19)) s1 += ex;
        if (v.x & (1 << 20)) s2 += ex;
    }
    sarr[n] = s0; sarr[N + n] = s1; sarr[2 * N + n] = s2;
}

// ---------------- propagation: wave per node, 4 edges x 16 lanes x float4 ----
// MODE = layer: 0 -> xout=x, out=emb+x; 1 -> xout=x, out+=x; 2 -> out=(out+x)/4
template <int MODE>
__global__ __launch_bounds__(256) void prop_kernel(const int* __restrict__ offsets,
                                                   const int2* __restrict__ csr,
                                                   const float* __restrict__ s_l,
                                                   const float* __restrict__ xin,
                                                   float* __restrict__ xout,
                                                   const float* __restrict__ emb,
                                                   float* __restrict__ out) {
    const int wid = (int)((blockIdx.x * blockDim.x + threadIdx.x) >> 6);
    if (wid >= N) return;
    const int lane = threadIdx.x & 63;
    const int g  = lane >> 4;   // edge slot 0..3
    const int sl = lane & 15;   // float4 slot within the 64-dim row
    const int beg = offsets[wid];
    const int end = offsets[wid + 1];
    const float inv = 1.0f / fmaxf(s_l[wid], 1e-16f);
    const int mbit = 1 << (18 + MODE);
    float4 acc = make_float4(0.f, 0.f, 0.f, 0.f);
    for (int p = beg + g; p < end; p += 4) {
        const int2 v = csr[p];
        if (v.x & mbit) {                       // retained this layer (reg test first)
            const int sidx = v.x & 0x3FFFF;
            if (s_l[sidx] > 0.f) {              // src-node flag (random 4B, L2-resident)
                const float c = __int_as_float(v.y) * inv;
                const float4 xv = *reinterpret_cast<const float4*>(
                    xin + ((size_t)sidx << 6) + (sl << 2));
                acc.x = fmaf(c, xv.x, acc.x);
                acc.y = fmaf(c, xv.y, acc.y);
                acc.z = fmaf(c, xv.z, acc.z);
                acc.w = fmaf(c, xv.w, acc.w);
            }
        }
    }
#pragma unroll
    for (int m = 16; m < 64; m <<= 1) {
        acc.x += __shfl_xor(acc.x, m, 64);
        acc.y += __shfl_xor(acc.y, m, 64);
        acc.z += __shfl_xor(acc.z, m, 64);
        acc.w += __shfl_xor(acc.w, m, 64);
    }
    if (lane < 16) {
        const size_t base = ((size_t)wid << 6) + (sl << 2);
        if (MODE == 0) {
            const float4 e4 = *reinterpret_cast<const float4*>(emb + base);
            *reinterpret_cast<float4*>(xout + base) = acc;
            float4 o = make_float4(e4.x + acc.x, e4.y + acc.y, e4.z + acc.z, e4.w + acc.w);
            *reinterpret_cast<float4*>(out + base) = o;
        } else if (MODE == 1) {
            *reinterpret_cast<float4*>(xout + base) = acc;
            float4 o = *reinterpret_cast<float4*>(out + base);
            o.x += acc.x; o.y += acc.y; o.z += acc.z; o.w += acc.w;
            *reinterpret_cast<float4*>(out + base) = o;
        } else {  // final layer: no xout write needed
            float4 o = *reinterpret_cast<float4*>(out + base);
            o.x = (o.x + acc.x) * 0.25f; o.y = (o.y + acc.y) * 0.25f;
            o.z = (o.z + acc.z) * 0.25f; o.w = (o.w + acc.w) * 0.25f;
            *reinterpret_cast<float4*>(out + base) = o;
        }
    }
}

// ---------------------------------------------------------------------------
extern "C" void kernel_launch(void* const* d_in, const int* in_sizes, int n_in,
                              void* d_out, int out_size, void* d_ws, size_t ws_size,
                              hipStream_t stream) {
    const float* emb  = (const float*)d_in[0];
    const float* attr = (const float*)d_in[1];
    const void*  ei   = d_in[2];
    const void*  maskp = d_in[3];
    float* out = (float*)d_out;

    char* w = (char*)d_ws;
    auto alloc = [&](size_t b) -> char* {
        char* p = w;
        w += (b + 255) & ~(size_t)255;
        return p;
    };
    int* flags   = (int*)alloc(2 * sizeof(int));
    int* cnt     = (int*)alloc((size_t)N * 4);
    int* offsets = (int*)alloc((size_t)(N + 1) * 4);
    int* cursor  = (int*)alloc((size_t)N * 4);
    int* bsums   = (int*)alloc(1024 * 4);
    int2* csr    = (int2*)alloc((size_t)E * 8);
    float* sarr  = (float*)alloc((size_t)3 * N * 4);
    float* x0    = (float*)alloc((size_t)N * 64 * 4);
    float* x1    = (float*)alloc((size_t)N * 64 * 4);
    if ((size_t)(w - (char*)d_ws) > ws_size) return;  // ~103 MiB required

    hipMemsetAsync(cnt, 0, (size_t)N * 4, stream);
    detect_kernel<<<1, 256, 0, stream>>>((const unsigned int*)ei, (const unsigned int*)maskp, flags);
    hist_kernel<<<2048, 256, 0, stream>>>(ei, flags, cnt);
    scan_k1<<<NB, 256, 0, stream>>>(cnt, bsums);
    scan_k2<<<1, 1024, 0, stream>>>(bsums);
    scan_k3<<<NB, 256, 0, stream>>>(cnt, bsums, offsets, cursor);
    scatter_kernel<<<2048, 256, 0, stream>>>(ei, maskp, attr, flags, cursor, csr);
    sums_kernel<<<NB, 256, 0, stream>>>(offsets, csr, sarr);
    prop_kernel<0><<<PB, 256, 0, stream>>>(offsets, csr, sarr,         emb, x0, emb, out);
    prop_kernel<1><<<PB, 256, 0, stream>>>(offsets, csr, sarr + N,     x0,  x1, emb, out);
    prop_kernel<2><<<PB, 256, 0, stream>>>(offsets, csr, sarr + 2 * N, x1,  x1, emb, out);
}